// Round 2
// baseline (344.105 us; speedup 1.0000x reference)
//
#include <hip/hip_runtime.h>

typedef unsigned short ushort_t;
typedef __attribute__((ext_vector_type(4))) float f32x4;
typedef __attribute__((ext_vector_type(8))) __bf16 bf16x8;

#define LAMBDA_INIT 0.7836057665316245f
#define ONE_MINUS_LI 0.21639423346837552f
#define SCALE 0.17677669529663687f  // 32^-0.5

__device__ inline ushort_t f2bf(float f) {
  union { float f; unsigned u; } v; v.f = f;
  unsigned r = (v.u + 0x7FFFu + ((v.u >> 16) & 1u)) >> 16;
  return (ushort_t)r;
}

__device__ inline f32x4 zero4() { f32x4 z = {0.f, 0.f, 0.f, 0.f}; return z; }

__device__ inline f32x4 mfma16(bf16x8 a, bf16x8 b, f32x4 c) {
  return __builtin_amdgcn_mfma_f32_16x16x32_bf16(a, b, c, 0, 0, 0);
}

__device__ inline void gload_lds16(const void* g, void* l) {
  __builtin_amdgcn_global_load_lds(
      (const __attribute__((address_space(1))) unsigned int*)g,
      (__attribute__((address_space(3))) unsigned int*)l, 16, 0, 0);
}

// ---------------- convert x (fp32 -> bf16) ----------------
__global__ __launch_bounds__(256) void cvt_f32_bf16(const float* __restrict__ in,
                                                    ushort_t* __restrict__ out, int n) {
  int i = (blockIdx.x * 256 + threadIdx.x) * 8;
  if (i >= n) return;
  float4 a = *(const float4*)(in + i);
  float4 b = *(const float4*)(in + i + 4);
  ushort_t r[8];
  r[0] = f2bf(a.x); r[1] = f2bf(a.y); r[2] = f2bf(a.z); r[3] = f2bf(a.w);
  r[4] = f2bf(b.x); r[5] = f2bf(b.y); r[6] = f2bf(b.z); r[7] = f2bf(b.w);
  uint4 pack;
  pack.x = (unsigned)r[0] | ((unsigned)r[1] << 16);
  pack.y = (unsigned)r[2] | ((unsigned)r[3] << 16);
  pack.z = (unsigned)r[4] | ((unsigned)r[5] << 16);
  pack.w = (unsigned)r[6] | ((unsigned)r[7] << 16);
  *(uint4*)(out + i) = pack;
}

// ---------------- transpose W (KxN fp32) -> WT (NxK bf16) ----------------
__global__ __launch_bounds__(256) void transpose_to_bf16(const float* __restrict__ W,
                                                         ushort_t* __restrict__ WT,
                                                         int K, int N) {
  __shared__ float tile[32][33];
  int n0 = blockIdx.x * 32, k0 = blockIdx.y * 32;
  int tx = threadIdx.x & 31, ty = threadIdx.x >> 5;  // ty in 0..7
#pragma unroll
  for (int j = 0; j < 4; ++j) {
    int k = k0 + ty + j * 8;
    tile[ty + j * 8][tx] = W[(size_t)k * N + n0 + tx];
  }
  __syncthreads();
#pragma unroll
  for (int j = 0; j < 4; ++j) {
    int n = n0 + ty + j * 8;
    WT[(size_t)n * K + k0 + tx] = f2bf(tile[tx][ty + j * 8]);
  }
}

// ---------------- GEMM: C[M,N] = A[M,K] * Bt[N,K]^T (+bias), bf16 in ----------------
template <int OUT_BF16>
__global__ __launch_bounds__(256) void gemm_bt(const ushort_t* __restrict__ A,
                                               const ushort_t* __restrict__ Bt,
                                               void* __restrict__ C,
                                               const float* __restrict__ bias,
                                               int M, int N, int K) {
  __shared__ ushort_t As[128 * 32];
  __shared__ ushort_t Bs[128 * 32];
  const int tid = threadIdx.x;
  const int wave = tid >> 6, lane = tid & 63;
  const int wr = wave >> 1, wc = wave & 1;
  const int lg = lane >> 4, ll = lane & 15;
  const int row0 = blockIdx.x * 128, col0 = blockIdx.y * 128;

  f32x4 acc[4][4];
#pragma unroll
  for (int m = 0; m < 4; ++m)
#pragma unroll
    for (int n = 0; n < 4; ++n) acc[m][n] = zero4();

  for (int k0 = 0; k0 < K; k0 += 32) {
    __syncthreads();
#pragma unroll
    for (int i = 0; i < 2; ++i) {
      int c = tid + i * 256;
      int r = c >> 2, ko = (c & 3) << 3;
      gload_lds16(A + (size_t)(row0 + r) * K + k0 + ko,
                  (char*)As + (size_t)(wave * 64 + i * 256) * 16);
      gload_lds16(Bt + (size_t)(col0 + r) * K + k0 + ko,
                  (char*)Bs + (size_t)(wave * 64 + i * 256) * 16);
    }
    __syncthreads();
    bf16x8 af[4], bf[4];
#pragma unroll
    for (int m = 0; m < 4; ++m)
      af[m] = *(const bf16x8*)(As + (wr * 64 + m * 16 + ll) * 32 + (lg << 3));
#pragma unroll
    for (int n = 0; n < 4; ++n)
      bf[n] = *(const bf16x8*)(Bs + (wc * 64 + n * 16 + ll) * 32 + (lg << 3));
#pragma unroll
    for (int m = 0; m < 4; ++m)
#pragma unroll
      for (int n = 0; n < 4; ++n) acc[m][n] = mfma16(af[m], bf[n], acc[m][n]);
  }

#pragma unroll
  for (int m = 0; m < 4; ++m) {
#pragma unroll
    for (int n = 0; n < 4; ++n) {
      int gc = col0 + wc * 64 + n * 16 + ll;
#pragma unroll
      for (int j = 0; j < 4; ++j) {
        int gr = row0 + wr * 64 + m * 16 + (lg << 2) + j;
        if (OUT_BF16) {
          ((ushort_t*)C)[(size_t)gr * N + gc] = f2bf(acc[m][n][j]);
        } else {
          ((float*)C)[(size_t)gr * N + gc] = acc[m][n][j] + bias[gc];
        }
      }
    }
  }
}

// ---------------- differential flash attention ----------------
__device__ inline void attn_step(const ushort_t* __restrict__ Ks, ushort_t* __restrict__ Pw,
                                 const bf16x8 q, const bf16x8 (*vf)[4],
                                 float* mS, float* lS, f32x4* oS, int lg, int ll) {
  f32x4 s[4];
#pragma unroll
  for (int nb = 0; nb < 4; ++nb) {
    bf16x8 kf = *(const bf16x8*)(Ks + (nb * 16 + ll) * 32 + (lg << 3));
    s[nb] = mfma16(q, kf, zero4());
  }
  float tm[4];
#pragma unroll
  for (int i = 0; i < 4; ++i)
    tm[i] = fmaxf(fmaxf(s[0][i], s[1][i]), fmaxf(s[2][i], s[3][i]));
#pragma unroll
  for (int mask = 1; mask < 16; mask <<= 1)
#pragma unroll
    for (int i = 0; i < 4; ++i) tm[i] = fmaxf(tm[i], __shfl_xor(tm[i], mask));
  float ef[4];
#pragma unroll
  for (int i = 0; i < 4; ++i) {
    float mn = fmaxf(mS[i], tm[i] * SCALE);
    ef[i] = __expf(mS[i] - mn);
    mS[i] = mn;
    lS[i] *= ef[i];
  }
#pragma unroll
  for (int nb = 0; nb < 4; ++nb)
#pragma unroll
    for (int i = 0; i < 4; ++i) oS[nb][i] *= ef[i];
  float rs[4] = {0.f, 0.f, 0.f, 0.f};
#pragma unroll
  for (int nb = 0; nb < 4; ++nb)
#pragma unroll
    for (int i = 0; i < 4; ++i) {
      float p = __expf(s[nb][i] * SCALE - mS[i]);
      rs[i] += p;
      Pw[((lg << 2) + i) * 72 + nb * 16 + ll] = f2bf(p);
    }
#pragma unroll
  for (int mask = 1; mask < 16; mask <<= 1)
#pragma unroll
    for (int i = 0; i < 4; ++i) rs[i] += __shfl_xor(rs[i], mask);
#pragma unroll
  for (int i = 0; i < 4; ++i) lS[i] += rs[i];
#pragma unroll
  for (int ks = 0; ks < 2; ++ks) {
    bf16x8 pf = *(const bf16x8*)(Pw + ll * 72 + ks * 32 + (lg << 3));
#pragma unroll
    for (int nb = 0; nb < 4; ++nb) oS[nb] = mfma16(pf, vf[ks][nb], oS[nb]);
  }
}

__global__ __launch_bounds__(256) void diff_attn(const ushort_t* __restrict__ qkv,
                                                 ushort_t* __restrict__ o,
                                                 const float* __restrict__ lq1,
                                                 const float* __restrict__ lk1,
                                                 const float* __restrict__ lq2,
                                                 const float* __restrict__ lk2,
                                                 const float* __restrict__ subln) {
  const int qt = blockIdx.x, h = blockIdx.y, b = blockIdx.z;
  const int tid = threadIdx.x, wave = tid >> 6, lane = tid & 63;
  const int lg = lane >> 4, ll = lane & 15;
  const int ld = 3072;
  const size_t base = (size_t)b * 2048 * ld;
  // qkv column layout: [3][H=16][64] -> q block 0..1023, k block 1024..2047, v 2048..3071
  // q/k further reshaped (2H, 32): Q1/K1 head h at h*32, Q2/K2 at 512 + h*32.
  const int cq1 = (h << 5);               // Q1
  const int cq2 = 512 + (h << 5);         // Q2
  const int ck1 = 1024 + (h << 5);        // K1
  const int ck2 = 1536 + (h << 5);        // K2
  const int cv = 2048 + (h << 6);         // V

  float sl1 = 0.f, sl2 = 0.f;
  for (int j = 0; j < 32; ++j) { sl1 += lq1[j] * lk1[j]; sl2 += lq2[j] * lk2[j]; }
  const float lam = __expf(sl1) - __expf(sl2) + LAMBDA_INIT;

  __shared__ ushort_t K1s[64 * 32];
  __shared__ ushort_t K2s[64 * 32];
  __shared__ ushort_t Vt[64 * 72];      // [d][t], padded stride 72
  __shared__ ushort_t Pl[4][16 * 72];   // per-wave P, padded stride 72

  const int qrow = qt * 64 + wave * 16 + ll;
  const ushort_t* qp = qkv + base + (size_t)qrow * ld;
  const bf16x8 q1f = *(const bf16x8*)(qp + cq1 + (lg << 3));
  const bf16x8 q2f = *(const bf16x8*)(qp + cq2 + (lg << 3));

  float m1[4], l1[4], m2[4], l2[4];
  f32x4 o1[4], o2[4];
#pragma unroll
  for (int i = 0; i < 4; ++i) { m1[i] = -1e30f; l1[i] = 0.f; m2[i] = -1e30f; l2[i] = 0.f; }
#pragma unroll
  for (int nb = 0; nb < 4; ++nb) { o1[nb] = zero4(); o2[nb] = zero4(); }

  for (int kv0 = 0; kv0 < 2048; kv0 += 64) {
    __syncthreads();
    {
      int c = tid;
      int r = c >> 2, ko = (c & 3) << 3;
      gload_lds16(qkv + base + (size_t)(kv0 + r) * ld + ck1 + ko, (char*)K1s + wave * 1024);
      gload_lds16(qkv + base + (size_t)(kv0 + r) * ld + ck2 + ko, (char*)K2s + wave * 1024);
    }
#pragma unroll
    for (int i = 0; i < 2; ++i) {
      int c = tid + i * 256;
      int t = c >> 3, d0 = (c & 7) << 3;
      uint4 v = *(const uint4*)(qkv + base + (size_t)(kv0 + t) * ld + cv + d0);
      const ushort_t* vv = (const ushort_t*)&v;
#pragma unroll
      for (int j = 0; j < 8; ++j) Vt[(d0 + j) * 72 + t] = vv[j];
    }
    __syncthreads();

    bf16x8 vf[2][4];
#pragma unroll
    for (int ks = 0; ks < 2; ++ks)
#pragma unroll
      for (int nb = 0; nb < 4; ++nb)
        vf[ks][nb] = *(const bf16x8*)(Vt + (nb * 16 + ll) * 72 + ks * 32 + (lg << 3));

    attn_step(K1s, &Pl[wave][0], q1f, vf, m1, l1, o1, lg, ll);
    attn_step(K2s, &Pl[wave][0], q2f, vf, m2, l2, o2, lg, ll);
  }

  // epilogue: combine, RMS-norm over 64 dims, scale, store bf16
  float ss[4] = {0.f, 0.f, 0.f, 0.f};
  f32x4 ov[4];
#pragma unroll
  for (int nb = 0; nb < 4; ++nb) {
#pragma unroll
    for (int i = 0; i < 4; ++i) {
      float a1 = o1[nb][i] / l1[i];
      float a2 = o2[nb][i] / l2[i];
      float x = a1 - lam * a2;
      ov[nb][i] = x;
      ss[i] += x * x;
    }
  }
#pragma unroll
  for (int mask = 1; mask < 16; mask <<= 1)
#pragma unroll
    for (int i = 0; i < 4; ++i) ss[i] += __shfl_xor(ss[i], mask);
  float nf[4];
#pragma unroll
  for (int i = 0; i < 4; ++i) nf[i] = rsqrtf(ss[i] * (1.f / 64.f) + 1e-5f);
  const size_t orow0 = (size_t)(b * 2048 + qt * 64 + wave * 16);
#pragma unroll
  for (int nb = 0; nb < 4; ++nb) {
    int d = nb * 16 + ll;
    float sw = subln[d] * ONE_MINUS_LI;
#pragma unroll
    for (int i = 0; i < 4; ++i) {
      int r = (lg << 2) + i;
      o[(orow0 + r) * 1024 + (h << 6) + d] = f2bf(ov[nb][i] * nf[i] * sw);
    }
  }
}

extern "C" void kernel_launch(void* const* d_in, const int* in_sizes, int n_in,
                              void* d_out, int out_size, void* d_ws, size_t ws_size,
                              hipStream_t stream) {
  const float* x      = (const float*)d_in[0];
  const float* W_qkv  = (const float*)d_in[1];
  const float* W_proj = (const float*)d_in[2];
  const float* b_proj = (const float*)d_in[3];
  const float* lq1    = (const float*)d_in[4];
  const float* lk1    = (const float*)d_in[5];
  const float* lq2    = (const float*)d_in[6];
  const float* lk2    = (const float*)d_in[7];
  const float* subln  = (const float*)d_in[8];

  char* ws = (char*)d_ws;
  ushort_t* xb     = (ushort_t*)(ws);                 //  8,388,608 B (4096x1024 bf16)
  ushort_t* qkvb   = (ushort_t*)(ws + 8388608);       // 25,165,824 B (4096x3072 bf16)
  ushort_t* wqkvT  = (ushort_t*)(ws + 33554432);      //  6,291,456 B (3072x1024 bf16)
  ushort_t* wprojT = (ushort_t*)(ws + 39845888);      //  2,097,152 B (1024x1024 bf16)
  ushort_t* ob     = (ushort_t*)(ws + 41943040);      //  8,388,608 B (4096x1024 bf16)

  cvt_f32_bf16<<<2048, 256, 0, stream>>>(x, xb, 4096 * 1024);
  transpose_to_bf16<<<dim3(96, 32), 256, 0, stream>>>(W_qkv, wqkvT, 1024, 3072);
  transpose_to_bf16<<<dim3(32, 32), 256, 0, stream>>>(W_proj, wprojT, 1024, 1024);
  gemm_bt<1><<<dim3(32, 24), 256, 0, stream>>>(xb, wqkvT, (void*)qkvb, nullptr, 4096, 3072, 1024);
  diff_attn<<<dim3(32, 16, 2), 256, 0, stream>>>(qkvb, ob, lq1, lk1, lq2, lk2, subln);
  gemm_bt<0><<<dim3(32, 8), 256, 0, stream>>>(ob, wprojT, d_out, b_proj, 4096, 1024, 1024);
}

// Round 3
// 213.377 us; speedup vs baseline: 1.6127x; 1.6127x over previous
//
#include <hip/hip_runtime.h>

typedef unsigned short ushort_t;
typedef unsigned int uint_t;
typedef __attribute__((ext_vector_type(4))) float f32x4;
typedef __attribute__((ext_vector_type(8))) __bf16 bf16x8;

#define LAMBDA_INIT 0.7836057665316245f
#define ONE_MINUS_LI 0.21639423346837552f
#define QSCALE_LOG2E 0.25505654442552663f  // 32^-0.5 * log2(e)

__device__ inline ushort_t f2bf(float f) {
  union { float f; unsigned u; } v; v.f = f;
  unsigned r = (v.u + 0x7FFFu + ((v.u >> 16) & 1u)) >> 16;
  return (ushort_t)r;
}

__device__ inline f32x4 zero4() { f32x4 z = {0.f, 0.f, 0.f, 0.f}; return z; }

__device__ inline f32x4 mfma16(bf16x8 a, bf16x8 b, f32x4 c) {
  return __builtin_amdgcn_mfma_f32_16x16x32_bf16(a, b, c, 0, 0, 0);
}

__device__ inline void gload_lds16(const void* g, void* l) {
  __builtin_amdgcn_global_load_lds(
      (const __attribute__((address_space(1))) unsigned int*)g,
      (__attribute__((address_space(3))) unsigned int*)l, 16, 0, 0);
}

// ---------------- convert x (fp32 -> bf16) ----------------
__global__ __launch_bounds__(256) void cvt_f32_bf16(const float* __restrict__ in,
                                                    ushort_t* __restrict__ out, int n) {
  int i = (blockIdx.x * 256 + threadIdx.x) * 8;
  if (i >= n) return;
  float4 a = *(const float4*)(in + i);
  float4 b = *(const float4*)(in + i + 4);
  ushort_t r[8];
  r[0] = f2bf(a.x); r[1] = f2bf(a.y); r[2] = f2bf(a.z); r[3] = f2bf(a.w);
  r[4] = f2bf(b.x); r[5] = f2bf(b.y); r[6] = f2bf(b.z); r[7] = f2bf(b.w);
  uint4 pack;
  pack.x = (unsigned)r[0] | ((unsigned)r[1] << 16);
  pack.y = (unsigned)r[2] | ((unsigned)r[3] << 16);
  pack.z = (unsigned)r[4] | ((unsigned)r[5] << 16);
  pack.w = (unsigned)r[6] | ((unsigned)r[7] << 16);
  *(uint4*)(out + i) = pack;
}

// ---------------- transpose W (KxN fp32) -> WT (NxK bf16) ----------------
__global__ __launch_bounds__(256) void transpose_to_bf16(const float* __restrict__ W,
                                                         ushort_t* __restrict__ WT,
                                                         int K, int N) {
  __shared__ float tile[32][33];
  int n0 = blockIdx.x * 32, k0 = blockIdx.y * 32;
  int tx = threadIdx.x & 31, ty = threadIdx.x >> 5;
#pragma unroll
  for (int j = 0; j < 4; ++j) {
    int k = k0 + ty + j * 8;
    tile[ty + j * 8][tx] = W[(size_t)k * N + n0 + tx];
  }
  __syncthreads();
#pragma unroll
  for (int j = 0; j < 4; ++j) {
    int n = n0 + ty + j * 8;
    WT[(size_t)n * K + k0 + tx] = f2bf(tile[tx][ty + j * 8]);
  }
}

// ---------------- GEMM: C[M,N] = A[M,K] * Bt[N,K]^T, bf16 in ----------------
// MODE 0: float out + bias (proj). MODE 1: qkv — q cols pre-scaled by
// QSCALE_LOG2E, q/k cols -> qk_out (ld 2048), v cols -> vt_out transposed
// [ (b*16+h)*64 + d ][ n ].
template <int MODE>
__global__ __launch_bounds__(256) void gemm_bt(const ushort_t* __restrict__ A,
                                               const ushort_t* __restrict__ Bt,
                                               void* __restrict__ C,
                                               ushort_t* __restrict__ vt_out,
                                               const float* __restrict__ bias,
                                               int M, int N, int K) {
  __shared__ ushort_t As[128 * 32];
  __shared__ ushort_t Bs[128 * 32];
  const int tid = threadIdx.x;
  const int wave = tid >> 6, lane = tid & 63;
  const int wr = wave >> 1, wc = wave & 1;
  const int lg = lane >> 4, ll = lane & 15;
  const int row0 = blockIdx.x * 128, col0 = blockIdx.y * 128;

  f32x4 acc[4][4];
#pragma unroll
  for (int m = 0; m < 4; ++m)
#pragma unroll
    for (int n = 0; n < 4; ++n) acc[m][n] = zero4();

  for (int k0 = 0; k0 < K; k0 += 32) {
    __syncthreads();
#pragma unroll
    for (int i = 0; i < 2; ++i) {
      int c = tid + i * 256;
      int r = c >> 2, ko = (c & 3) << 3;
      gload_lds16(A + (size_t)(row0 + r) * K + k0 + ko,
                  (char*)As + (size_t)(wave * 64 + i * 256) * 16);
      gload_lds16(Bt + (size_t)(col0 + r) * K + k0 + ko,
                  (char*)Bs + (size_t)(wave * 64 + i * 256) * 16);
    }
    __syncthreads();
    bf16x8 af[4], bf[4];
#pragma unroll
    for (int m = 0; m < 4; ++m)
      af[m] = *(const bf16x8*)(As + (wr * 64 + m * 16 + ll) * 32 + (lg << 3));
#pragma unroll
    for (int n = 0; n < 4; ++n)
      bf[n] = *(const bf16x8*)(Bs + (wc * 64 + n * 16 + ll) * 32 + (lg << 3));
#pragma unroll
    for (int m = 0; m < 4; ++m)
#pragma unroll
      for (int n = 0; n < 4; ++n) acc[m][n] = mfma16(af[m], bf[n], acc[m][n]);
  }

#pragma unroll
  for (int m = 0; m < 4; ++m) {
#pragma unroll
    for (int n = 0; n < 4; ++n) {
      int gc = col0 + wc * 64 + n * 16 + ll;
#pragma unroll
      for (int j = 0; j < 4; ++j) {
        int gr = row0 + wr * 64 + m * 16 + (lg << 2) + j;
        float v = acc[m][n][j];
        if (MODE == 0) {
          ((float*)C)[(size_t)gr * N + gc] = v + bias[gc];
        } else {
          if (gc < 2048) {
            float sc = (gc < 1024) ? QSCALE_LOG2E : 1.0f;
            ((ushort_t*)C)[(size_t)gr * 2048 + gc] = f2bf(v * sc);
          } else {
            int hv = (gc - 2048) >> 6, dv = (gc - 2048) & 63;
            int bb = gr >> 11, nn = gr & 2047;
            vt_out[((size_t)((bb * 16 + hv) * 64 + dv)) * 2048 + nn] = f2bf(v);
          }
        }
      }
    }
  }
}

// ---------------- differential flash attention (swapped-QK, static max) ----------------
__global__ __launch_bounds__(256) void diff_attn(const ushort_t* __restrict__ qk,
                                                 const ushort_t* __restrict__ vt,
                                                 ushort_t* __restrict__ o,
                                                 const float* __restrict__ lq1,
                                                 const float* __restrict__ lk1,
                                                 const float* __restrict__ lq2,
                                                 const float* __restrict__ lk2,
                                                 const float* __restrict__ subln) {
  const int qt = blockIdx.x, h = blockIdx.y, b = blockIdx.z;
  const int tid = threadIdx.x, wave = tid >> 6, lane = tid & 63;
  const int lg = lane >> 4, ll = lane & 15;

  const size_t qbase = (size_t)b * 2048 * 2048;
  const int cq1 = (h << 5), cq2 = 512 + (h << 5);
  const int ck1 = 1024 + (h << 5), ck2 = 1536 + (h << 5);
  const size_t vbase = (size_t)((b * 16 + h) * 64) * 2048;

  float sl1 = 0.f, sl2 = 0.f;
  for (int j = 0; j < 32; ++j) { sl1 += lq1[j] * lk1[j]; sl2 += lq2[j] * lk2[j]; }
  const float lam = __expf(sl1) - __expf(sl2) + LAMBDA_INIT;

  __shared__ ushort_t Ks[64 * 64];   // [kv r][8 chunks: 0-3 K1, 4-7 K2], XOR-8 swizzled
  __shared__ ushort_t Vs[64 * 64];   // [d r][8 t-chunks], XOR-8 swizzled
  __shared__ ushort_t Pl[4][16 * 72];

  // Q fragments: swapped layout -> Q is the B operand (same frag as before).
  const int qrow = qt * 64 + wave * 16 + ll;
  const bf16x8 q1f = *(const bf16x8*)(qk + qbase + (size_t)qrow * 2048 + cq1 + (lg << 3));
  const bf16x8 q2f = *(const bf16x8*)(qk + qbase + (size_t)qrow * 2048 + cq2 + (lg << 3));

  f32x4 o1[4], o2[4];
#pragma unroll
  for (int nb = 0; nb < 4; ++nb) { o1[nb] = zero4(); o2[nb] = zero4(); }
  float l1p = 0.f, l2p = 0.f;
  ushort_t* Pw = &Pl[wave][0];

  // staging: slot s -> row r = s>>3, chunk c = s&7; LDS[r][c] holds global chunk c^(r&7)
  const int s0 = tid, s1 = tid + 256;
  const int r0 = s0 >> 3, c0 = (s0 & 7) ^ (r0 & 7);
  const int r1 = s1 >> 3, c1 = (s1 & 7) ^ (r1 & 7);
  const int kc0 = ((c0 & 4) ? ck2 : ck1) + ((c0 & 3) << 3);
  const int kc1 = ((c1 & 4) ? ck2 : ck1) + ((c1 & 3) << 3);
  const int ub0 = (wave << 6) * 16;
  const int ub1 = ((wave << 6) + 256) * 16;

  for (int kv0 = 0; kv0 < 2048; kv0 += 64) {
    __syncthreads();
    gload_lds16(qk + qbase + (size_t)(kv0 + r0) * 2048 + kc0, (char*)Ks + ub0);
    gload_lds16(qk + qbase + (size_t)(kv0 + r1) * 2048 + kc1, (char*)Ks + ub1);
    gload_lds16(vt + vbase + (size_t)r0 * 2048 + kv0 + (c0 << 3), (char*)Vs + ub0);
    gload_lds16(vt + vbase + (size_t)r1 * 2048 + kv0 + (c1 << 3), (char*)Vs + ub1);
    __syncthreads();

    bf16x8 vf[2][4];
#pragma unroll
    for (int ks = 0; ks < 2; ++ks)
#pragma unroll
      for (int nb = 0; nb < 4; ++nb) {
        int d = nb * 16 + ll;
        int cc = (ks * 4 + lg) ^ (d & 7);
        vf[ks][nb] = *(const bf16x8*)(Vs + d * 64 + (cc << 3));
      }

#pragma unroll
    for (int pass = 0; pass < 2; ++pass) {
      const bf16x8 qf = pass ? q2f : q1f;
      f32x4* oacc = pass ? o2 : o1;
      f32x4 s[4];
#pragma unroll
      for (int nb = 0; nb < 4; ++nb) {
        int R = nb * 16 + ll;
        int cK = (lg ^ (R & 7)) ^ (pass << 2);
        bf16x8 kf = *(const bf16x8*)(Ks + R * 64 + (cK << 3));
        s[nb] = mfma16(kf, qf, zero4());   // D: row=k (4lg+i), col=q (ll)
      }
      float part = 0.f;
#pragma unroll
      for (int nb = 0; nb < 4; ++nb) {
        float e0 = exp2f(s[nb][0]), e1 = exp2f(s[nb][1]);
        float e2 = exp2f(s[nb][2]), e3 = exp2f(s[nb][3]);
        part += (e0 + e1) + (e2 + e3);
        uint_t a0 = __float_as_uint(e0) + 0x8000u;
        uint_t a1 = __float_as_uint(e1) + 0x8000u;
        uint_t a2 = __float_as_uint(e2) + 0x8000u;
        uint_t a3 = __float_as_uint(e3) + 0x8000u;
        uint2 w;
        w.x = __builtin_amdgcn_perm(a1, a0, 0x07060302u);
        w.y = __builtin_amdgcn_perm(a3, a2, 0x07060302u);
        // P[q=ll][k = nb*16 + lg*4 .. +3]
        *(uint2*)(Pw + ll * 72 + nb * 16 + (lg << 2)) = w;
      }
      if (pass) l2p += part; else l1p += part;
#pragma unroll
      for (int ks = 0; ks < 2; ++ks) {
        bf16x8 pf = *(const bf16x8*)(Pw + ll * 72 + ks * 32 + (lg << 3));
#pragma unroll
        for (int nb = 0; nb < 4; ++nb) oacc[nb] = mfma16(pf, vf[ks][nb], oacc[nb]);
      }
    }
  }

  // l lives per-lane for q = ll; finish reduction over lg, then fetch per-row.
  float l1 = l1p; l1 += __shfl_xor(l1, 16); l1 += __shfl_xor(l1, 32);
  float l2 = l2p; l2 += __shfl_xor(l2, 16); l2 += __shfl_xor(l2, 32);
  float i1[4], i2[4];
#pragma unroll
  for (int j = 0; j < 4; ++j) {
    int src = (lane & 48) | ((lg << 2) + j);   // lane with ll == q-row
    i1[j] = 1.f / __shfl(l1, src);
    i2[j] = 1.f / __shfl(l2, src);
  }

  float ss[4] = {0.f, 0.f, 0.f, 0.f};
  f32x4 ov[4];
#pragma unroll
  for (int nb = 0; nb < 4; ++nb) {
#pragma unroll
    for (int j = 0; j < 4; ++j) {
      float x = o1[nb][j] * i1[j] - lam * (o2[nb][j] * i2[j]);
      ov[nb][j] = x;
      ss[j] += x * x;
    }
  }
#pragma unroll
  for (int mask = 1; mask < 16; mask <<= 1)
#pragma unroll
    for (int j = 0; j < 4; ++j) ss[j] += __shfl_xor(ss[j], mask);
  float nf[4];
#pragma unroll
  for (int j = 0; j < 4; ++j) nf[j] = rsqrtf(ss[j] * (1.f / 64.f) + 1e-5f);
  const size_t orow0 = (size_t)(b * 2048 + qt * 64 + wave * 16);
#pragma unroll
  for (int nb = 0; nb < 4; ++nb) {
    int d = nb * 16 + ll;
    float sw = subln[d] * ONE_MINUS_LI;
#pragma unroll
    for (int j = 0; j < 4; ++j) {
      int r = (lg << 2) + j;
      o[(orow0 + r) * 1024 + (h << 6) + d] = f2bf(ov[nb][j] * nf[j] * sw);
    }
  }
}

extern "C" void kernel_launch(void* const* d_in, const int* in_sizes, int n_in,
                              void* d_out, int out_size, void* d_ws, size_t ws_size,
                              hipStream_t stream) {
  const float* x      = (const float*)d_in[0];
  const float* W_qkv  = (const float*)d_in[1];
  const float* W_proj = (const float*)d_in[2];
  const float* b_proj = (const float*)d_in[3];
  const float* lq1    = (const float*)d_in[4];
  const float* lk1    = (const float*)d_in[5];
  const float* lq2    = (const float*)d_in[6];
  const float* lk2    = (const float*)d_in[7];
  const float* subln  = (const float*)d_in[8];

  char* ws = (char*)d_ws;
  ushort_t* xb     = (ushort_t*)(ws);                 //  8,388,608 B (4096x1024 bf16)
  ushort_t* qkb    = (ushort_t*)(ws + 8388608);       // 16,777,216 B (4096x2048 bf16, q|k)
  ushort_t* vtb    = (ushort_t*)(ws + 25165824);      //  8,388,608 B (V^T: [2*16*64][2048])
  ushort_t* wqkvT  = (ushort_t*)(ws + 33554432);      //  6,291,456 B (3072x1024 bf16)
  ushort_t* wprojT = (ushort_t*)(ws + 39845888);      //  2,097,152 B (1024x1024 bf16)
  ushort_t* ob     = (ushort_t*)(ws + 41943040);      //  8,388,608 B (4096x1024 bf16)

  cvt_f32_bf16<<<2048, 256, 0, stream>>>(x, xb, 4096 * 1024);
  transpose_to_bf16<<<dim3(96, 32), 256, 0, stream>>>(W_qkv, wqkvT, 1024, 3072);
  transpose_to_bf16<<<dim3(32, 32), 256, 0, stream>>>(W_proj, wprojT, 1024, 1024);
  gemm_bt<1><<<dim3(32, 24), 256, 0, stream>>>(xb, wqkvT, (void*)qkb, vtb, nullptr, 4096, 3072, 1024);
  diff_attn<<<dim3(32, 16, 2), 256, 0, stream>>>(qkb, vtb, ob, lq1, lk1, lq2, lk2, subln);
  gemm_bt<0><<<dim3(32, 8), 256, 0, stream>>>(ob, wprojT, d_out, nullptr, b_proj, 4096, 1024, 1024);
}

// Round 4
// 178.197 us; speedup vs baseline: 1.9310x; 1.1974x over previous
//
#include <hip/hip_runtime.h>

typedef unsigned short ushort_t;
typedef unsigned int uint_t;
typedef __attribute__((ext_vector_type(4))) float f32x4;
typedef __attribute__((ext_vector_type(8))) __bf16 bf16x8;

#define LAMBDA_INIT 0.7836057665316245f
#define ONE_MINUS_LI 0.21639423346837552f
#define QSCALE_LOG2E 0.25505654442552663f  // 32^-0.5 * log2(e)

__device__ inline ushort_t f2bf(float f) {
  union { float f; unsigned u; } v; v.f = f;
  unsigned r = (v.u + 0x7FFFu + ((v.u >> 16) & 1u)) >> 16;
  return (ushort_t)r;
}

// bare v_exp_f32 (args bounded, no libm range fixup needed)
__device__ inline float fexp2(float x) {
  float r;
  asm("v_exp_f32 %0, %1" : "=v"(r) : "v"(x));
  return r;
}

// pack 2 f32 -> 2 bf16 (RNE), lo in low half
__device__ inline uint_t cvtpk(float lo, float hi) {
  uint_t r;
  asm("v_cvt_pk_bf16_f32 %0, %1, %2" : "=v"(r) : "v"(lo), "v"(hi));
  return r;
}

__device__ inline f32x4 zero4() { f32x4 z = {0.f, 0.f, 0.f, 0.f}; return z; }

__device__ inline f32x4 mfma16(bf16x8 a, bf16x8 b, f32x4 c) {
  return __builtin_amdgcn_mfma_f32_16x16x32_bf16(a, b, c, 0, 0, 0);
}

__device__ inline void gload_lds16(const void* g, void* l) {
  __builtin_amdgcn_global_load_lds(
      (const __attribute__((address_space(1))) unsigned int*)g,
      (__attribute__((address_space(3))) unsigned int*)l, 16, 0, 0);
}

// ---------------- convert x (fp32 -> bf16) ----------------
__global__ __launch_bounds__(256) void cvt_f32_bf16(const float* __restrict__ in,
                                                    ushort_t* __restrict__ out, int n) {
  int i = (blockIdx.x * 256 + threadIdx.x) * 8;
  if (i >= n) return;
  float4 a = *(const float4*)(in + i);
  float4 b = *(const float4*)(in + i + 4);
  uint4 pack;
  pack.x = cvtpk(a.x, a.y);
  pack.y = cvtpk(a.z, a.w);
  pack.z = cvtpk(b.x, b.y);
  pack.w = cvtpk(b.z, b.w);
  *(uint4*)(out + i) = pack;
}

// ---------------- transpose W (KxN fp32) -> WT (NxK bf16) ----------------
__global__ __launch_bounds__(256) void transpose_to_bf16(const float* __restrict__ W,
                                                         ushort_t* __restrict__ WT,
                                                         int K, int N) {
  __shared__ float tile[32][33];
  int n0 = blockIdx.x * 32, k0 = blockIdx.y * 32;
  int tx = threadIdx.x & 31, ty = threadIdx.x >> 5;
#pragma unroll
  for (int j = 0; j < 4; ++j) {
    int k = k0 + ty + j * 8;
    tile[ty + j * 8][tx] = W[(size_t)k * N + n0 + tx];
  }
  __syncthreads();
#pragma unroll
  for (int j = 0; j < 4; ++j) {
    int n = n0 + ty + j * 8;
    WT[(size_t)n * K + k0 + tx] = f2bf(tile[tx][ty + j * 8]);
  }
}

// ---------------- GEMM: C[M,N] = A[M,K] * Bt[N,K]^T, bf16 in ----------------
// MODE 0: float out + bias (proj). MODE 1: qkv — q cols pre-scaled by
// QSCALE_LOG2E, q/k cols -> qk_out (ld 2048), v cols -> vt_out transposed
// [ (b*16+h)*64 + d ][ n ].
template <int MODE>
__global__ __launch_bounds__(256) void gemm_bt(const ushort_t* __restrict__ A,
                                               const ushort_t* __restrict__ Bt,
                                               void* __restrict__ C,
                                               ushort_t* __restrict__ vt_out,
                                               const float* __restrict__ bias,
                                               int M, int N, int K) {
  __shared__ ushort_t As[128 * 32];
  __shared__ ushort_t Bs[128 * 32];
  const int tid = threadIdx.x;
  const int wave = tid >> 6, lane = tid & 63;
  const int wr = wave >> 1, wc = wave & 1;
  const int lg = lane >> 4, ll = lane & 15;
  const int row0 = blockIdx.x * 128, col0 = blockIdx.y * 128;

  f32x4 acc[4][4];
#pragma unroll
  for (int m = 0; m < 4; ++m)
#pragma unroll
    for (int n = 0; n < 4; ++n) acc[m][n] = zero4();

  for (int k0 = 0; k0 < K; k0 += 32) {
    __syncthreads();
#pragma unroll
    for (int i = 0; i < 2; ++i) {
      int c = tid + i * 256;
      int r = c >> 2, ko = (c & 3) << 3;
      gload_lds16(A + (size_t)(row0 + r) * K + k0 + ko,
                  (char*)As + (size_t)(wave * 64 + i * 256) * 16);
      gload_lds16(Bt + (size_t)(col0 + r) * K + k0 + ko,
                  (char*)Bs + (size_t)(wave * 64 + i * 256) * 16);
    }
    __syncthreads();
    bf16x8 af[4], bf[4];
#pragma unroll
    for (int m = 0; m < 4; ++m)
      af[m] = *(const bf16x8*)(As + (wr * 64 + m * 16 + ll) * 32 + (lg << 3));
#pragma unroll
    for (int n = 0; n < 4; ++n)
      bf[n] = *(const bf16x8*)(Bs + (wc * 64 + n * 16 + ll) * 32 + (lg << 3));
#pragma unroll
    for (int m = 0; m < 4; ++m)
#pragma unroll
      for (int n = 0; n < 4; ++n) acc[m][n] = mfma16(af[m], bf[n], acc[m][n]);
  }

#pragma unroll
  for (int m = 0; m < 4; ++m) {
#pragma unroll
    for (int n = 0; n < 4; ++n) {
      int gc = col0 + wc * 64 + n * 16 + ll;
      int gr0 = row0 + wr * 64 + m * 16 + (lg << 2);
      if (MODE == 0) {
#pragma unroll
        for (int j = 0; j < 4; ++j)
          ((float*)C)[(size_t)(gr0 + j) * N + gc] = acc[m][n][j] + bias[gc];
      } else {
        if (gc < 2048) {
          float sc = (gc < 1024) ? QSCALE_LOG2E : 1.0f;
#pragma unroll
          for (int j = 0; j < 4; ++j)
            ((ushort_t*)C)[(size_t)(gr0 + j) * 2048 + gc] = f2bf(acc[m][n][j] * sc);
        } else {
          // V columns -> transposed store, 4 consecutive n packed into 8B
          int hv = (gc - 2048) >> 6, dv = (gc - 2048) & 63;
          int bb = gr0 >> 11, nn = gr0 & 2047;
          uint2 w;
          w.x = cvtpk(acc[m][n][0], acc[m][n][1]);
          w.y = cvtpk(acc[m][n][2], acc[m][n][3]);
          *(uint2*)(vt_out + ((size_t)((bb * 16 + hv) * 64 + dv)) * 2048 + nn) = w;
        }
      }
    }
  }
}

// ---------------- differential flash attention (swapped-QK, static max, dbuf) ----------------
__global__ __launch_bounds__(256) void diff_attn(const ushort_t* __restrict__ qk,
                                                 const ushort_t* __restrict__ vt,
                                                 ushort_t* __restrict__ o,
                                                 const float* __restrict__ lq1,
                                                 const float* __restrict__ lk1,
                                                 const float* __restrict__ lq2,
                                                 const float* __restrict__ lk2,
                                                 const float* __restrict__ subln) {
  const int qt = blockIdx.x, h = blockIdx.y, b = blockIdx.z;
  const int tid = threadIdx.x, wave = tid >> 6, lane = tid & 63;
  const int lg = lane >> 4, ll = lane & 15;

  const size_t qbase = (size_t)b * 2048 * 2048;
  const int cq1 = (h << 5), cq2 = 512 + (h << 5);
  const int ck1 = 1024 + (h << 5), ck2 = 1536 + (h << 5);
  const size_t vbase = (size_t)((b * 16 + h) * 64) * 2048;

  float sl1 = 0.f, sl2 = 0.f;
  for (int j = 0; j < 32; ++j) { sl1 += lq1[j] * lk1[j]; sl2 += lq2[j] * lk2[j]; }
  const float lam = __expf(sl1) - __expf(sl2) + LAMBDA_INIT;

  __shared__ ushort_t Ks[2][64 * 64];   // [kv r][8 chunks: 0-3 K1, 4-7 K2], XOR-8 swizzled
  __shared__ ushort_t Vs[2][64 * 64];   // [d r][8 t-chunks], XOR-8 swizzled
  __shared__ ushort_t Pl[4][16 * 72];

  // Q fragments (B-operand of swapped QK^T)
  const int qrow = qt * 64 + wave * 16 + ll;
  const bf16x8 q1f = *(const bf16x8*)(qk + qbase + (size_t)qrow * 2048 + cq1 + (lg << 3));
  const bf16x8 q2f = *(const bf16x8*)(qk + qbase + (size_t)qrow * 2048 + cq2 + (lg << 3));

  f32x4 o1[4], o2[4];
#pragma unroll
  for (int nb = 0; nb < 4; ++nb) { o1[nb] = zero4(); o2[nb] = zero4(); }
  float l1p = 0.f, l2p = 0.f;
  ushort_t* Pw = &Pl[wave][0];

  // staging geometry: slot s -> row r = s>>3, lds chunk s&7 holds global chunk (s&7)^(r&7)
  const int s0 = tid, s1 = tid + 256;
  const int r0 = s0 >> 3, c0 = (s0 & 7) ^ (r0 & 7);
  const int r1 = s1 >> 3, c1 = (s1 & 7) ^ (r1 & 7);
  const int kc0 = ((c0 & 4) ? ck2 : ck1) + ((c0 & 3) << 3);
  const int kc1 = ((c1 & 4) ? ck2 : ck1) + ((c1 & 3) << 3);
  const int ub0 = (wave << 6) * 16;         // byte offset of this wave's 64 slots
  const int ub1 = ((wave << 6) + 256) * 16;

#define STAGE(buf, kv0)                                                                   \
  do {                                                                                    \
    gload_lds16(qk + qbase + (size_t)((kv0) + r0) * 2048 + kc0, (char*)Ks[buf] + ub0);    \
    gload_lds16(qk + qbase + (size_t)((kv0) + r1) * 2048 + kc1, (char*)Ks[buf] + ub1);    \
    gload_lds16(vt + vbase + (size_t)r0 * 2048 + (kv0) + (c0 << 3), (char*)Vs[buf] + ub0);\
    gload_lds16(vt + vbase + (size_t)r1 * 2048 + (kv0) + (c1 << 3), (char*)Vs[buf] + ub1);\
  } while (0)

  STAGE(0, 0);
  __syncthreads();

  int cur = 0;
  for (int t = 0; t < 32; ++t) {
    if (t < 31) STAGE(cur ^ 1, (t + 1) * 64);  // prefetch next tile (flies under compute)

    const ushort_t* Kc = Ks[cur];
    const ushort_t* Vc = Vs[cur];

    bf16x8 vf[2][4];
#pragma unroll
    for (int ks = 0; ks < 2; ++ks)
#pragma unroll
      for (int nb = 0; nb < 4; ++nb) {
        int d = nb * 16 + ll;
        int cc = (ks * 4 + lg) ^ (d & 7);
        vf[ks][nb] = *(const bf16x8*)(Vc + d * 64 + (cc << 3));
      }

#pragma unroll
    for (int pass = 0; pass < 2; ++pass) {
      const bf16x8 qf = pass ? q2f : q1f;
      f32x4* oacc = pass ? o2 : o1;
      f32x4 s[4];
#pragma unroll
      for (int nb = 0; nb < 4; ++nb) {
        int R = nb * 16 + ll;
        int cK = (lg ^ (R & 7)) ^ (pass << 2);
        bf16x8 kf = *(const bf16x8*)(Kc + R * 64 + (cK << 3));
        s[nb] = mfma16(kf, qf, zero4());   // D: row=k (4lg+i), col=q (ll)
      }
      float part = 0.f;
#pragma unroll
      for (int nb = 0; nb < 4; ++nb) {
        float e0 = fexp2(s[nb][0]), e1 = fexp2(s[nb][1]);
        float e2 = fexp2(s[nb][2]), e3 = fexp2(s[nb][3]);
        part += (e0 + e1) + (e2 + e3);
        uint2 w;
        w.x = cvtpk(e0, e1);
        w.y = cvtpk(e2, e3);
        // P[q=ll][k = nb*16 + lg*4 .. +3]
        *(uint2*)(Pw + ll * 72 + nb * 16 + (lg << 2)) = w;
      }
      if (pass) l2p += part; else l1p += part;
#pragma unroll
      for (int ks = 0; ks < 2; ++ks) {
        bf16x8 pf = *(const bf16x8*)(Pw + ll * 72 + ks * 32 + (lg << 3));
#pragma unroll
        for (int nb = 0; nb < 4; ++nb) oacc[nb] = mfma16(pf, vf[ks][nb], oacc[nb]);
      }
    }
    __syncthreads();   // implicit vmcnt(0)+lgkmcnt(0) drain: next tile's loads are done
    cur ^= 1;
  }
#undef STAGE

  // l lives per-lane for q = ll; finish reduction over lg, then fetch per-row.
  float l1 = l1p; l1 += __shfl_xor(l1, 16); l1 += __shfl_xor(l1, 32);
  float l2 = l2p; l2 += __shfl_xor(l2, 16); l2 += __shfl_xor(l2, 32);
  float i1[4], i2[4];
#pragma unroll
  for (int j = 0; j < 4; ++j) {
    int src = (lane & 48) | ((lg << 2) + j);   // lane with ll == q-row
    i1[j] = 1.f / __shfl(l1, src);
    i2[j] = 1.f / __shfl(l2, src);
  }

  float ss[4] = {0.f, 0.f, 0.f, 0.f};
  f32x4 ov[4];
#pragma unroll
  for (int nb = 0; nb < 4; ++nb) {
#pragma unroll
    for (int j = 0; j < 4; ++j) {
      float x = o1[nb][j] * i1[j] - lam * (o2[nb][j] * i2[j]);
      ov[nb][j] = x;
      ss[j] += x * x;
    }
  }
#pragma unroll
  for (int mask = 1; mask < 16; mask <<= 1)
#pragma unroll
    for (int j = 0; j < 4; ++j) ss[j] += __shfl_xor(ss[j], mask);
  float nf[4];
#pragma unroll
  for (int j = 0; j < 4; ++j) nf[j] = rsqrtf(ss[j] * (1.f / 64.f) + 1e-5f);
  const size_t orow0 = (size_t)(b * 2048 + qt * 64 + wave * 16);
#pragma unroll
  for (int nb = 0; nb < 4; ++nb) {
    int d = nb * 16 + ll;
    float sw = subln[d] * ONE_MINUS_LI;
#pragma unroll
    for (int j = 0; j < 4; ++j) {
      int r = (lg << 2) + j;
      o[(orow0 + r) * 1024 + (h << 6) + d] = f2bf(ov[nb][j] * nf[j] * sw);
    }
  }
}

extern "C" void kernel_launch(void* const* d_in, const int* in_sizes, int n_in,
                              void* d_out, int out_size, void* d_ws, size_t ws_size,
                              hipStream_t stream) {
  const float* x      = (const float*)d_in[0];
  const float* W_qkv  = (const float*)d_in[1];
  const float* W_proj = (const float*)d_in[2];
  const float* b_proj = (const float*)d_in[3];
  const float* lq1    = (const float*)d_in[4];
  const float* lk1    = (const float*)d_in[5];
  const float* lq2    = (const float*)d_in[6];
  const float* lk2    = (const float*)d_in[7];
  const float* subln  = (const float*)d_in[8];

  char* ws = (char*)d_ws;
  ushort_t* xb     = (ushort_t*)(ws);                 //  8,388,608 B (4096x1024 bf16)
  ushort_t* qkb    = (ushort_t*)(ws + 8388608);       // 16,777,216 B (4096x2048 bf16, q|k)
  ushort_t* vtb    = (ushort_t*)(ws + 25165824);      //  8,388,608 B (V^T: [2*16*64][2048])
  ushort_t* wqkvT  = (ushort_t*)(ws + 33554432);      //  6,291,456 B (3072x1024 bf16)
  ushort_t* wprojT = (ushort_t*)(ws + 39845888);      //  2,097,152 B (1024x1024 bf16)
  ushort_t* ob     = (ushort_t*)(ws + 41943040);      //  8,388,608 B (4096x1024 bf16)

  cvt_f32_bf16<<<2048, 256, 0, stream>>>(x, xb, 4096 * 1024);
  transpose_to_bf16<<<dim3(96, 32), 256, 0, stream>>>(W_qkv, wqkvT, 1024, 3072);
  transpose_to_bf16<<<dim3(32, 32), 256, 0, stream>>>(W_proj, wprojT, 1024, 1024);
  gemm_bt<1><<<dim3(32, 24), 256, 0, stream>>>(xb, wqkvT, (void*)qkb, vtb, nullptr, 4096, 3072, 1024);
  diff_attn<<<dim3(32, 16, 2), 256, 0, stream>>>(qkb, vtb, ob, lq1, lk1, lq2, lk2, subln);
  gemm_bt<0><<<dim3(32, 8), 256, 0, stream>>>(ob, wprojT, d_out, nullptr, b_proj, 4096, 1024, 1024);
}